// Round 7
// baseline (2711.895 us; speedup 1.0000x reference)
//
#include <hip/hip_runtime.h>
#include <hip/hip_bf16.h>
#include <stdint.h>

#define T_STEPS 512
#define BATCH   256
#define HID     256

#define NRWG   64      // recurrence WGs: 32 batch-groups x 2 halves (2 gates each)
#define NWWG   192     // xgemm producer WGs
#define NWG    256
#define RING   4       // ring slots
#define CHUNK  8       // time steps per chunk
#define NCHUNK 64
#define TPC    64      // tiles per chunk: (8*256/128) * (1024/256)
#define SLOT_F (CHUNK*256*1024)   // floats per ring slot (8 MB)

using short8 = __attribute__((ext_vector_type(8))) short;
using f32x4  = __attribute__((ext_vector_type(4))) float;

#define VMCNT0() asm volatile("s_waitcnt vmcnt(0)" ::: "memory")

__device__ inline unsigned short f2bf(float f) {
  unsigned u = __float_as_uint(f);
  unsigned r = (u + 0x7fffu + ((u >> 16) & 1u)) >> 16;
  return (unsigned short)r;
}
__device__ inline float sigm(float x)   { return __builtin_amdgcn_rcpf(1.0f + __expf(-x)); }
__device__ inline float tanh_f(float x) { return 2.0f * __builtin_amdgcn_rcpf(1.0f + __expf(-2.0f * x)) - 1.0f; }

__device__ inline int ld_rlx(const int* p) {
  return __hip_atomic_load(p, __ATOMIC_RELAXED, __HIP_MEMORY_SCOPE_AGENT);
}
__device__ inline void add_rlx(int* p, int v) {
  __hip_atomic_fetch_add(p, v, __ATOMIC_RELAXED, __HIP_MEMORY_SCOPE_AGENT);
}
__device__ inline float ldg_coh(const float* p) {
  return __hip_atomic_load(p, __ATOMIC_RELAXED, __HIP_MEMORY_SCOPE_AGENT);
}
__device__ inline void stg_coh(float* p, float v) {
  __hip_atomic_store(p, v, __ATOMIC_RELAXED, __HIP_MEMORY_SCOPE_AGENT);
}
// 16B LLC store (proven round 5)
__device__ inline void st16_coh(f32x4* p, f32x4 v) {
  asm volatile("global_store_dwordx4 %0, %1, off sc0 sc1" :: "v"(p), "v"(v) : "memory");
}

// h LDS swizzle: frag-linear layout, XOR bits 4..5 with bits 8..9 (proven r5)
__device__ inline int hswz(int byte) { return byte ^ (((byte >> 8) & 3) << 4); }

struct RecSm {
  unsigned short hL[4096];      // h frag-linear, 16 batch-cols x 256 k (8 real rows)
  float z[8][520];              // z[row][512 cols + pad]
};
struct GemSm { unsigned short aL[4096]; unsigned short bL[8192]; };

// ---------------- prep: pack weights + zero flags/packets ----------------
// Wfull : [1024 cols][768 k] bf16 ; cvec : [1024] = bias + theta
__global__ __launch_bounds__(256) void prep_kernel(
    const float* __restrict__ Wf, const float* __restrict__ Wi,
    const float* __restrict__ Wg, const float* __restrict__ Wo,
    const float* __restrict__ bf_, const float* __restrict__ bi_,
    const float* __restrict__ bg_, const float* __restrict__ bo_,
    const float* __restrict__ thf, const float* __restrict__ thi,
    const float* __restrict__ thg, const float* __restrict__ tho,
    unsigned short* __restrict__ Wfull, float* __restrict__ cvec,
    int* __restrict__ flags, float* __restrict__ pk)
{
  int j = blockIdx.x;            // 0..1023 output col
  int g = j >> 8, col = j & 255;
  const float* W  = (g==0)?Wf:(g==1)?Wi:(g==2)?Wg:Wo;
  const float* bb = (g==0)?bf_:(g==1)?bi_:(g==2)?bg_:bo_;
  const float* th = (g==0)?thf:(g==1)?thi:(g==2)?thg:tho;
  const float* wrow = W + (size_t)col * 768;
  for (int k = threadIdx.x; k < 768; k += blockDim.x)
    Wfull[(size_t)j * 768 + k] = f2bf(wrow[k]);
  if (threadIdx.x == 0) cvec[j] = bb[col] + th[col];
  if (j == 0) for (int i = threadIdx.x; i < 512; i += 256) flags[i] = 0;
  // zero 3MB packet region (kills stale embedded seqs across graph replays)
  float* pz = pk + (size_t)j * 768;
  for (int i = threadIdx.x; i < 768; i += 256) pz[i] = 0.0f;
}

// ---------------- persistent kernel ----------------
// blocks 0..63   : recurrence (bg = bid>>1 rows bg*8..+7; half = bid&1 gates {2h,2h+1})
// blocks 64..255 : xgemm producers filling the Zx ring
__global__ __launch_bounds__(512, 2) void persist_kernel(
    const float* __restrict__ X,
    const unsigned short* __restrict__ Wfull,
    const float* __restrict__ cvec,
    float* __restrict__ ring,
    f32x4* __restrict__ pk,       // [2 par][32 bg][2 half][8 wv][64 lane][3] f32x4 = 3MB
    int* __restrict__ done,       // [64]
    int* __restrict__ consumed,   // [1]
    float* __restrict__ out)
{
  __shared__ union { RecSm rec; GemSm gem; } sm;

  int bid = blockIdx.x, tid = threadIdx.x;
  int lane = tid & 63, wv = tid >> 6;       // 8 waves
  int l15 = lane & 15, lk = lane >> 4;

  if (bid < NRWG) {
    // ================= recurrence =================
    int bg = bid >> 1, half = bid & 1;

    for (int i = tid; i < 4096; i += 512) sm.rec.hL[i] = 0;

    // Wh fragments -> registers: wave wv covers cols half*512 + wv*64 .. +63
    short8 af[4][8];
#pragma unroll
    for (int st = 0; st < 4; ++st)
#pragma unroll
      for (int kk = 0; kk < 8; ++kk)
        af[st][kk] = *(const short8*)(Wfull +
            (size_t)(half*512 + wv*64 + st*16 + l15)*768 + 512 + kk*32 + lk*8);

    float creg[4] = {0.f, 0.f, 0.f, 0.f};   // c-state: row=wv, col=s*64+lane
    float zx[8];
    __syncthreads();

    for (int t = 0; t < T_STEPS; ++t) {
      int cIdx = t >> 3;
      if ((t & 7) == 0) {
        if (tid == 0) { while (ld_rlx(&done[cIdx]) < TPC) __builtin_amdgcn_s_sleep(1); }
        __syncthreads();
        const float* zp = ring + (size_t)(cIdx & (RING-1))*SLOT_F
                        + ((size_t)(bg*8 + wv))*1024 + half*512 + lane;
#pragma unroll
        for (int s = 0; s < 8; ++s) zx[s] = ldg_coh(zp + s*64);
      }

      // ---- MFMA: z = Wh_cols x h_rows (4 strips/wave, K=256) ----
      short8 bfr[8];
#pragma unroll
      for (int kk = 0; kk < 8; ++kk)
        bfr[kk] = *(const short8*)((const char*)sm.rec.hL + hswz(kk*1024 + lane*16));
      f32x4 acc[4];
#pragma unroll
      for (int st = 0; st < 4; ++st) acc[st] = (f32x4){0.f,0.f,0.f,0.f};
#pragma unroll
      for (int kk = 0; kk < 8; ++kk)
#pragma unroll
        for (int st = 0; st < 4; ++st)
          acc[st] = __builtin_amdgcn_mfma_f32_16x16x32_bf16(af[st][kk], bfr[kk], acc[st], 0, 0, 0);
      if (l15 < 8) {   // D: col(batch)=l15, strip col = lk*4+reg
#pragma unroll
        for (int st = 0; st < 4; ++st)
          *(f32x4*)&sm.rec.z[l15][wv*64 + st*16 + lk*4] = acc[st];
      }
      __syncthreads();

      // ---- scan (wave wv = batch row wv): 8 segments = 2 gates x 4 ----
      float v[8];
#pragma unroll
      for (int s = 0; s < 8; ++s)
        v[s] = __cosf(sm.rec.z[wv][s*64 + lane] + zx[s]);
#pragma unroll
      for (int off = 1; off < 64; off <<= 1) {
        float u[8];
#pragma unroll
        for (int s = 0; s < 8; ++s) u[s] = __shfl_up(v[s], (unsigned)off, 64);
        if (lane >= off) {
#pragma unroll
          for (int s = 0; s < 8; ++s) v[s] *= u[s];
        }
      }
      // cross-segment carries per gate
      float tA0 = __shfl(v[0], 63, 64), tA1 = __shfl(v[1], 63, 64), tA2 = __shfl(v[2], 63, 64);
      float tB0 = __shfl(v[4], 63, 64), tB1 = __shfl(v[5], 63, 64), tB2 = __shfl(v[6], 63, 64);
      float pA2 = tA0*tA1, pA3 = pA2*tA2;
      float pB2 = tB0*tB1, pB3 = pB2*tB2;
      float aA[4] = {v[0], v[1]*tA0, v[2]*pA2, v[3]*pA3};
      float aB[4] = {v[4], v[5]*tB0, v[6]*pB2, v[7]*pB3};
      if (half == 0) {  // gates f,i : sigmoid both
#pragma unroll
        for (int s = 0; s < 4; ++s) { aA[s] = sigm(aA[s]); aB[s] = sigm(aB[s]); }
      } else {          // gates g,o : tanh, sigmoid
#pragma unroll
        for (int s = 0; s < 4; ++s) { aA[s] = tanh_f(aA[s]); aB[s] = sigm(aB[s]); }
      }

      // ---- publish: 3x16B packets with embedded seq (wave-local, LLC) ----
      int par = t & 1, T1 = t + 1;
      float seqf = __int_as_float(T1);
      size_t idx = ((((size_t)par*32 + bg)*2 + half)*8 + wv)*64 + lane;
      f32x4* myp = pk + idx*3;
      f32x4 P0 = {aA[0], aA[1], aA[2], seqf};
      f32x4 P1 = {aA[3], aB[0], aB[1], seqf};
      f32x4 P2 = {aB[2], aB[3], 0.f,  seqf};
      st16_coh(myp,     P0);
      st16_coh(myp + 1, P1);
      st16_coh(myp + 2, P2);

      // zx prefetch for t+1 (non-boundary; overlaps the peer poll)
      if (((t+1) & 7) != 0 && t+1 < T_STEPS) {
        const float* zp = ring + (size_t)(cIdx & (RING-1))*SLOT_F
                        + ((size_t)(((t+1) & 7)*256) + bg*8 + wv)*1024 + half*512 + lane;
#pragma unroll
        for (int s = 0; s < 8; ++s) zx[s] = ldg_coh(zp + s*64);
      }

      // ---- poll peer half's packets (embedded seq, proven r5 pattern) ----
      size_t pidx = ((((size_t)par*32 + bg)*2 + (half^1))*8 + wv)*64 + lane;
      const f32x4* pp = pk + pidx*3;
      f32x4 q0, q1, q2;
      do {
        asm volatile(
          "global_load_dwordx4 %0, %3, off sc0 sc1\n\t"
          "global_load_dwordx4 %1, %4, off sc0 sc1\n\t"
          "global_load_dwordx4 %2, %5, off sc0 sc1\n\t"
          "s_waitcnt vmcnt(0)"
          : "=&v"(q0), "=&v"(q1), "=&v"(q2)
          : "v"(pp), "v"(pp + 1), "v"(pp + 2)
          : "memory");
      } while (__float_as_int(q0[3]) < T1 || __float_as_int(q1[3]) < T1 ||
               __float_as_int(q2[3]) < T1);
      float p0 = q0[0], p1 = q0[1], p2 = q0[2], p3 = q1[0];
      float p4 = q1[1], p5 = q1[2], p6 = q2[0], p7 = q2[1];

      // gather: f,i,g,o per segment s (hidden col = s*64+lane)
      float fv[4], iv[4], gv[4], ov[4];
      if (half == 0) {
#pragma unroll
        for (int s = 0; s < 4; ++s) { fv[s] = aA[s]; iv[s] = aB[s]; }
        gv[0]=p0; gv[1]=p1; gv[2]=p2; gv[3]=p3;
        ov[0]=p4; ov[1]=p5; ov[2]=p6; ov[3]=p7;
      } else {
#pragma unroll
        for (int s = 0; s < 4; ++s) { gv[s] = aA[s]; ov[s] = aB[s]; }
        fv[0]=p0; fv[1]=p1; fv[2]=p2; fv[3]=p3;
        iv[0]=p4; iv[1]=p5; iv[2]=p6; iv[3]=p7;
      }

      int brow = bg*8 + wv;
#pragma unroll
      for (int s = 0; s < 4; ++s) {
        float cn = fv[s]*creg[s] + iv[s]*gv[s];
        creg[s] = cn;
        float h = ov[s]*tanh_f(cn);
        int k = s*64 + lane;
        int byte = (k >> 5)*1024 + ((((k >> 3) & 3)*16 + wv)*16) + (k & 7)*2;
        *(unsigned short*)((char*)sm.rec.hL + hswz(byte)) = f2bf(h);
        if (half == 0) {
          out[(size_t)t*(BATCH*HID) + (size_t)brow*256 + k] = h;
          if (t == T_STEPS-1) {
            out[(size_t)T_STEPS*(BATCH*HID) + (size_t)brow*256 + k] = h;
            out[(size_t)T_STEPS*(BATCH*HID) + BATCH*HID + (size_t)brow*256 + k] = cn;
          }
        }
      }
      if ((t & 7) == 7 && tid == 0) add_rlx(consumed, 1);
      __syncthreads();   // hL(t) complete before next MFMA; z reads done
    }
  } else {
    // ================= xgemm producers (128x256 tiles, frag-linear LDS; proven r5) =====
    int w0 = bid - NRWG;
    int wr = wv >> 2, wc = wv & 3;          // 2 x 4 wave grid, 64x64 per wave
    int rA = tid >> 2, kA = (tid & 3) * 8;  // A staging: 128 rows x 32 k
    int rB = tid >> 1, kB = (tid & 1) * 16; // B staging: 256 cols x 32 k

    for (int gt = w0; gt < NCHUNK * TPC; gt += NWWG) {
      int c  = gt >> 6;
      int tl = gt & 63;
      int tm = tl >> 2, tn = tl & 3;

      int need = NRWG * (c - RING + 1);
      if (need > 0) {
        if (tid == 0) { while (ld_rlx(consumed) < need) __builtin_amdgcn_s_sleep(8); }
        __syncthreads();
      }

      const float* Xb = X + ((size_t)c*(CHUNK*256) + (size_t)tm*128) * 512;
      float* slotp = ring + (size_t)(c & (RING-1)) * SLOT_F;

      f32x4 acc[4][4];
#pragma unroll
      for (int mi = 0; mi < 4; ++mi)
#pragma unroll
        for (int ni = 0; ni < 4; ++ni) acc[mi][ni] = (f32x4){0.f,0.f,0.f,0.f};

      int slotA = (rA >> 4)*1024 + ((tid & 3)*16 + (rA & 15))*16;
      int baseB = (rB >> 4)*1024;
      int kO = kB >> 3;
      int slotB0 = baseB + ((kO    )*16 + (rB & 15))*16;
      int slotB1 = baseB + ((kO + 1)*16 + (rB & 15))*16;

      for (int kb = 0; kb < 512; kb += 32) {
        const float* ap = Xb + (size_t)rA*512 + kb + kA;
        f32x4 v0 = *(const f32x4*)ap;
        f32x4 v1 = *(const f32x4*)(ap + 4);
        unsigned short t8[8];
        t8[0]=f2bf(v0[0]); t8[1]=f2bf(v0[1]); t8[2]=f2bf(v0[2]); t8[3]=f2bf(v0[3]);
        t8[4]=f2bf(v1[0]); t8[5]=f2bf(v1[1]); t8[6]=f2bf(v1[2]); t8[7]=f2bf(v1[3]);
        *(short8*)((char*)sm.gem.aL + slotA) = *(short8*)t8;
        const unsigned short* bp = Wfull + (size_t)(tn*256 + rB)*768 + kb + kB;
        *(short8*)((char*)sm.gem.bL + slotB0) = *(const short8*)bp;
        *(short8*)((char*)sm.gem.bL + slotB1) = *(const short8*)(bp + 8);
        __syncthreads();

        short8 afr[4], bfr4[4];
#pragma unroll
        for (int mi = 0; mi < 4; ++mi)
          afr[mi]  = *(const short8*)((const char*)sm.gem.aL + (wr*4 + mi)*1024 + lane*16);
#pragma unroll
        for (int ni = 0; ni < 4; ++ni)
          bfr4[ni] = *(const short8*)((const char*)sm.gem.bL + (wc*4 + ni)*1024 + lane*16);
#pragma unroll
        for (int mi = 0; mi < 4; ++mi)
#pragma unroll
          for (int ni = 0; ni < 4; ++ni)
            acc[mi][ni] = __builtin_amdgcn_mfma_f32_16x16x32_bf16(afr[mi], bfr4[ni], acc[mi][ni], 0, 0, 0);
        __syncthreads();
      }

#pragma unroll
      for (int mi = 0; mi < 4; ++mi) {
#pragma unroll
        for (int ni = 0; ni < 4; ++ni) {
          int col = tn*256 + wc*64 + ni*16 + l15;
          float cv = cvec[col];
#pragma unroll
          for (int reg = 0; reg < 4; ++reg) {
            int row = tm*128 + wr*64 + mi*16 + lk*4 + reg;
            stg_coh(&slotp[(size_t)row*1024 + col], acc[mi][ni][reg] + cv);
          }
        }
      }
      VMCNT0();
      __syncthreads();                       // all waves' stores at LLC
      if (tid == 0) add_rlx(&done[c], 1);
    }
  }
}

// ---------------- host ----------------
extern "C" void kernel_launch(void* const* d_in, const int* in_sizes, int n_in,
                              void* d_out, int out_size, void* d_ws, size_t ws_size,
                              hipStream_t stream) {
  const float* x   = (const float*)d_in[0];
  const float* Wf  = (const float*)d_in[1];
  const float* bf_ = (const float*)d_in[2];
  const float* thf = (const float*)d_in[3];
  const float* Wi  = (const float*)d_in[4];
  const float* bi_ = (const float*)d_in[5];
  const float* thi = (const float*)d_in[6];
  const float* Wg  = (const float*)d_in[7];
  const float* bg_ = (const float*)d_in[8];
  const float* thg = (const float*)d_in[9];
  const float* Wo  = (const float*)d_in[10];
  const float* bo_ = (const float*)d_in[11];
  const float* tho = (const float*)d_in[12];
  float* out = (float*)d_out;

  char* ws = (char*)d_ws;
  unsigned short* Wfull = (unsigned short*)ws;            // 1.5 MB
  float* cvec  = (float*)(ws + 1572864);                  // 4 KB
  int*   flags = (int*)(ws + 1576960);                    // 2 KB
  f32x4* pk    = (f32x4*)(ws + 2097152);                  // 3 MB packets
  float* ring  = (float*)(ws + 8388608);                  // RING x 8 MB = 32 MB

  prep_kernel<<<1024, 256, 0, stream>>>(Wf, Wi, Wg, Wo, bf_, bi_, bg_, bo_,
                                        thf, thi, thg, tho, Wfull, cvec, flags,
                                        (float*)pk);
  persist_kernel<<<NWG, 512, 0, stream>>>(x, Wfull, cvec, ring, pk,
                                          flags, flags + 128, out);
}